// Round 2
// baseline (857.197 us; speedup 1.0000x reference)
//
#include <hip/hip_runtime.h>
#include <math.h>

// ---------------------------------------------------------------------------
// GCNSim: 2-layer GCN via dst-bucketed edge keys + LDS-atomic aggregation
// NPB = 64 nodes per bucket; key = src (17b) | local_dst (6b) << 17
// ---------------------------------------------------------------------------

#define NPB 64
#define NB_PAD 2048
#define BATCH 16384

__global__ void zero_kernel(int* __restrict__ p, int c) {
    int i = blockIdx.x * 256 + threadIdx.x;
    if (i < c) p[i] = 0;
}

__global__ void needed_kernel(const int* __restrict__ nodes, int* __restrict__ needed, int nsel) {
    int i = blockIdx.x * 256 + threadIdx.x;
    if (i < nsel) needed[nodes[i]] = 1;
}

// ---- Pass A: per-bucket edge histogram (LDS-aggregated)
__global__ __launch_bounds__(256) void histA_kernel(const int* __restrict__ ei,
                                                    int* __restrict__ bhist, int nE, int nb) {
    __shared__ int h[NB_PAD];
    int tid = threadIdx.x;
    for (int t = tid; t < nb; t += 256) h[t] = 0;
    __syncthreads();
    int base = blockIdx.x * 4096;
    for (int t = tid; t < 4096; t += 256) {
        int e = base + t;
        if (e < nE) atomicAdd(&h[ei[nE + e] >> 6], 1);
    }
    __syncthreads();
    for (int t = tid; t < nb; t += 256) { int c = h[t]; if (c) atomicAdd(&bhist[t], c); }
}

// ---- Pass B: exclusive scan of bucket counts -> boffs[nb+1], gcur copy
__global__ __launch_bounds__(256) void scanB_kernel(const int* __restrict__ bhist,
                                                    int* __restrict__ boffs,
                                                    int* __restrict__ gcur, int nb) {
    int t = threadIdx.x;
    int v[8], s = 0;
    #pragma unroll
    for (int i = 0; i < 8; ++i) { int c = t * 8 + i; v[i] = (c < nb) ? bhist[c] : 0; s += v[i]; }
    int lane = t & 63, wid = t >> 6;
    int incl = s;
    for (int d = 1; d < 64; d <<= 1) { int u = __shfl_up(incl, (unsigned)d, 64); if (lane >= d) incl += u; }
    __shared__ int ws[4];
    if (lane == 63) ws[wid] = incl;
    __syncthreads();
    int add = 0;
    for (int w = 0; w < wid; ++w) add += ws[w];
    incl += add;
    int excl = incl - s;
    #pragma unroll
    for (int i = 0; i < 8; ++i) {
        int c = t * 8 + i;
        if (c < nb) { boffs[c] = excl; gcur[c] = excl; }
        excl += v[i];
    }
    if (t == 0) boffs[nb] = ws[0] + ws[1] + ws[2] + ws[3];
}

// ---- Pass C: batch-sorted scatter of packed keys into bucket regions
__global__ __launch_bounds__(256) void scatterC_kernel(const int* __restrict__ ei,
                                                       int* __restrict__ gcur,
                                                       int* __restrict__ keys, int nE, int nb) {
    __shared__ unsigned short sidx[BATCH];   // 32 KB
    __shared__ int hist[NB_PAD];
    __shared__ int lstart[NB_PAD];
    __shared__ int cursor[NB_PAD];
    __shared__ int gbase[NB_PAD];
    __shared__ int ws2[4];
    int tid = threadIdx.x;
    int base = blockIdx.x * BATCH;
    int cnt = nE - base; if (cnt > BATCH) cnt = BATCH;
    for (int t = tid; t < nb; t += 256) hist[t] = 0;
    __syncthreads();
    for (int t = tid; t < cnt; t += 256)
        atomicAdd(&hist[ei[nE + base + t] >> 6], 1);
    __syncthreads();
    // exclusive scan hist -> lstart, cursor
    {
        int v[8], s = 0;
        #pragma unroll
        for (int i = 0; i < 8; ++i) { int c = tid * 8 + i; v[i] = (c < nb) ? hist[c] : 0; s += v[i]; }
        int lane = tid & 63, wid = tid >> 6;
        int incl = s;
        for (int d = 1; d < 64; d <<= 1) { int u = __shfl_up(incl, (unsigned)d, 64); if (lane >= d) incl += u; }
        if (lane == 63) ws2[wid] = incl;
        __syncthreads();
        int add = 0;
        for (int w = 0; w < wid; ++w) add += ws2[w];
        incl += add;
        int excl = incl - s;
        #pragma unroll
        for (int i = 0; i < 8; ++i) {
            int c = tid * 8 + i;
            if (c < nb) { lstart[c] = excl; cursor[c] = excl; }
            excl += v[i];
        }
    }
    __syncthreads();
    // reserve global space per bucket
    for (int t = tid; t < nb; t += 256) {
        int c = hist[t];
        gbase[t] = c ? atomicAdd(&gcur[t], c) : 0;
    }
    // insert local indices in bucket-major order
    for (int t = tid; t < cnt; t += 256) {
        int b = ei[nE + base + t] >> 6;
        int pos = atomicAdd(&cursor[b], 1);
        sidx[pos] = (unsigned short)t;
    }
    __syncthreads();
    // write out packed keys, coalesced within bucket segments
    for (int j = tid; j < cnt; j += 256) {
        int e = sidx[j];
        int d = ei[nE + base + e];
        int srcv = ei[base + e];
        int b = d >> 6;
        keys[gbase[b] + (j - lstart[b])] = srcv | ((d & 63) << 17);
    }
}

// ---- Pass C2: per-node degree (from grouped keys) -> dis
__global__ __launch_bounds__(256) void disC2_kernel(const int* __restrict__ keys,
                                                    const int* __restrict__ boffs,
                                                    float* __restrict__ dis, int n) {
    __shared__ int cnt[NPB];
    int tid = threadIdx.x, b = blockIdx.x;
    if (tid < NPB) cnt[tid] = 1;  // self-loop
    __syncthreads();
    int off = boffs[b], end = boffs[b + 1];
    for (int t = off + tid; t < end; t += 256)
        atomicAdd(&cnt[keys[t] >> 17], 1);
    __syncthreads();
    int node = b * NPB + tid;
    if (tid < NPB && node < n) dis[node] = rsqrtf((float)cnt[tid]);
}

// ---- hw1 = x @ w1  [N,256]x[256,32] -> [N,32]
__global__ __launch_bounds__(256) void hw1_kernel(const float* __restrict__ x,
                                                  const float* __restrict__ w1,
                                                  float* __restrict__ hw1, int n) {
    __shared__ float w1s[256 * 32];
    __shared__ float xs[8 * 256];
    int tid = threadIdx.x;
    for (int t = tid * 4; t < 8192; t += 1024)
        *(float4*)&w1s[t] = *(const float4*)&w1[t];
    int row0 = blockIdx.x * 8;
    for (int t = tid * 4; t < 2048; t += 1024) {
        int r = t >> 8, c = t & 255;
        int row = row0 + r;
        if (row < n) *(float4*)&xs[t] = *(const float4*)&x[(size_t)row * 256 + c];
    }
    __syncthreads();
    int r = tid >> 5, k = tid & 31;
    int row = row0 + r;
    if (row >= n) return;
    float acc = 0.f;
    #pragma unroll 4
    for (int c = 0; c < 256; c += 4) {
        float4 xv = *(float4*)&xs[r * 256 + c];
        acc += xv.x * w1s[(c    ) * 32 + k];
        acc += xv.y * w1s[(c + 1) * 32 + k];
        acc += xv.z * w1s[(c + 2) * 32 + k];
        acc += xv.w * w1s[(c + 3) * 32 + k];
    }
    hw1[(size_t)row * 32 + k] = acc;
}

// ---- Pass D: layer-1 aggregate (LDS atomics) + ReLU + fused @w2 -> hw2
__global__ __launch_bounds__(256) void aggD_kernel(const float* __restrict__ hw1,
                                                   const float* __restrict__ dis,
                                                   const int* __restrict__ keys,
                                                   const int* __restrict__ boffs,
                                                   const float* __restrict__ b1,
                                                   const float* __restrict__ w2,
                                                   float* __restrict__ hw2, int n) {
    __shared__ float acc[NPB * 32];   // 8 KB
    __shared__ int kbuf[256];
    __shared__ float w2s[512];
    __shared__ float b1s[32];
    int tid = threadIdx.x, b = blockIdx.x;
    for (int t = tid; t < NPB * 32; t += 256) acc[t] = 0.f;
    for (int t = tid; t < 512; t += 256) w2s[t] = w2[t];
    if (tid < 32) b1s[tid] = b1[tid];
    __syncthreads();
    int off = boffs[b], end = boffs[b + 1];
    int lane5 = tid & 31, eslot = tid >> 5;   // 8 edges per round
    for (int base = off; base < end; base += 256) {
        int c = end - base; if (c > 256) c = 256;
        if (tid < c) kbuf[tid] = keys[base + tid];
        __syncthreads();
        if (c == 256) {
            #pragma unroll 8
            for (int sub = 0; sub < 256; sub += 8) {
                int key = kbuf[sub + eslot];
                int srcv = key & 0x1FFFF;
                int ld = key >> 17;
                float v = hw1[srcv * 32 + lane5] * dis[srcv];
                atomicAdd(&acc[ld * 32 + lane5], v);
            }
        } else {
            for (int sub = 0; sub < c; sub += 8) {
                int e2 = sub + eslot;
                if (e2 < c) {
                    int key = kbuf[e2];
                    int srcv = key & 0x1FFFF;
                    int ld = key >> 17;
                    float v = hw1[srcv * 32 + lane5] * dis[srcv];
                    atomicAdd(&acc[ld * 32 + lane5], v);
                }
            }
        }
        __syncthreads();
    }
    int node0 = b * NPB;
    // finalize h1 = relu(dn*(acc + self*dn) + b1), in place
    for (int t = tid; t < NPB * 32; t += 256) {
        int ld = t >> 5, k = t & 31;
        int node = node0 + ld;
        if (node < n) {
            float dn = dis[node];
            float h1 = dn * (acc[t] + hw1[node * 32 + k] * dn) + b1s[k];
            acc[t] = fmaxf(h1, 0.f);
        }
    }
    __syncthreads();
    // hw2 = h1 @ w2
    for (int t = tid; t < NPB * 16; t += 256) {
        int ld = t >> 4, kk = t & 15;
        int node = node0 + ld;
        if (node < n) {
            float a = 0.f;
            #pragma unroll
            for (int cc = 0; cc < 32; ++cc) a += acc[ld * 32 + cc] * w2s[cc * 16 + kk];
            hw2[node * 16 + kk] = a;
        }
    }
}

// ---- Pass E: layer-2 aggregate, selected-dst only -> h2 (aliases hw1 buffer)
__global__ __launch_bounds__(256) void aggE_kernel(const float* __restrict__ hw2,
                                                   const float* __restrict__ dis,
                                                   const int* __restrict__ keys,
                                                   const int* __restrict__ boffs,
                                                   const int* __restrict__ needed,
                                                   const float* __restrict__ b2,
                                                   float* __restrict__ h2, int n) {
    __shared__ float acc[NPB * 16];   // 4 KB
    __shared__ int q[256];
    __shared__ int qn;
    __shared__ int fl[NPB];
    int tid = threadIdx.x, b = blockIdx.x;
    int node0 = b * NPB;
    if (tid < NPB) { int node = node0 + tid; fl[tid] = (node < n) ? needed[node] : 0; }
    for (int t = tid; t < NPB * 16; t += 256) acc[t] = 0.f;
    if (tid == 0) qn = 0;
    __syncthreads();
    int off = boffs[b], end = boffs[b + 1];
    int lane4 = tid & 15, eslot = tid >> 4;   // 16 edges per round
    for (int base = off; base < end; base += 256) {
        int c = end - base; if (c > 256) c = 256;
        bool want = false; int key = 0;
        if (tid < c) { key = keys[base + tid]; want = (fl[key >> 17] != 0); }
        if (want) { int p = atomicAdd(&qn, 1); q[p] = key; }
        __syncthreads();
        int m = qn;
        for (int sub = 0; sub < m; sub += 16) {
            int e2 = sub + eslot;
            if (e2 < m) {
                int kk = q[e2];
                int srcv = kk & 0x1FFFF;
                int ld = kk >> 17;
                float v = hw2[srcv * 16 + lane4] * dis[srcv];
                atomicAdd(&acc[ld * 16 + lane4], v);
            }
        }
        __syncthreads();
        if (tid == 0) qn = 0;
        __syncthreads();
    }
    for (int t = tid; t < NPB * 16; t += 256) {
        int ld = t >> 4, k = t & 15;
        int node = node0 + ld;
        if (node < n && fl[ld]) {
            float dn = dis[node];
            h2[node * 16 + k] = dn * (acc[t] + hw2[node * 16 + k] * dn) + b2[k];
        }
    }
}

// ---- pairwise concat + MoE1 + MoE2 + log_softmax
__global__ __launch_bounds__(256) void pair_moe_kernel(const float* __restrict__ h2,
                                                       const int* __restrict__ nodes,
                                                       const float* __restrict__ gate1_w,
                                                       const float* __restrict__ e1_w,
                                                       const float* __restrict__ e1_b,
                                                       const float* __restrict__ gate2_w,
                                                       const float* __restrict__ e2_w,
                                                       const float* __restrict__ e2_b,
                                                       float* __restrict__ out1,
                                                       float* __restrict__ out2, int M) {
    __shared__ float hjs[50 * 16];
    __shared__ float g1s[32 * 4];
    __shared__ float e1ws[4 * 32 * 16];
    __shared__ float e1bs[4 * 16];
    __shared__ float g2s[16 * 4];
    __shared__ float e2ws[4 * 16 * 2];
    __shared__ float e2bs[4 * 2];
    int tid = threadIdx.x;
    for (int t = tid; t < 800; t += 256) { int j = t >> 4, c = t & 15; hjs[t] = h2[nodes[j] * 16 + c]; }
    for (int t = tid; t < 128; t += 256) g1s[t] = gate1_w[t];
    for (int t = tid; t < 2048; t += 256) e1ws[t] = e1_w[t];
    for (int t = tid; t < 64; t += 256) e1bs[t] = e1_b[t];
    for (int t = tid; t < 64; t += 256) g2s[t] = gate2_w[t];
    for (int t = tid; t < 128; t += 256) e2ws[t] = e2_w[t];
    if (tid < 8) e2bs[tid] = e2_b[tid];
    __syncthreads();

    int m = blockIdx.x * 256 + tid;
    if (m >= M) return;
    int i = m / 50, j = m - i * 50;

    float xs[32];
    int ni = nodes[i];
    float4 a0 = *(const float4*)&h2[ni * 16];
    float4 a1 = *(const float4*)&h2[ni * 16 + 4];
    float4 a2 = *(const float4*)&h2[ni * 16 + 8];
    float4 a3 = *(const float4*)&h2[ni * 16 + 12];
    xs[0]=a0.x; xs[1]=a0.y; xs[2]=a0.z; xs[3]=a0.w;
    xs[4]=a1.x; xs[5]=a1.y; xs[6]=a1.z; xs[7]=a1.w;
    xs[8]=a2.x; xs[9]=a2.y; xs[10]=a2.z; xs[11]=a2.w;
    xs[12]=a3.x; xs[13]=a3.y; xs[14]=a3.z; xs[15]=a3.w;
    #pragma unroll
    for (int c = 0; c < 16; ++c) xs[16 + c] = hjs[j * 16 + c];

    #pragma unroll
    for (int c = 0; c < 32; c += 4)
        *(float4*)&out2[(size_t)m * 32 + c] = make_float4(xs[c], xs[c+1], xs[c+2], xs[c+3]);

    float g[4] = {0.f, 0.f, 0.f, 0.f};
    #pragma unroll
    for (int c = 0; c < 32; ++c) {
        float xv = xs[c];
        #pragma unroll
        for (int e = 0; e < 4; ++e) g[e] += xv * g1s[c * 4 + e];
    }
    int idx = 0; float best = g[0];
    #pragma unroll
    for (int e = 1; e < 4; ++e) if (g[e] > best) { best = g[e]; idx = e; }
    float z[16];
    #pragma unroll
    for (int o = 0; o < 16; ++o) {
        float a = e1bs[idx * 16 + o];
        #pragma unroll
        for (int c = 0; c < 32; ++c) a += xs[c] * e1ws[(idx * 32 + c) * 16 + o];
        z[o] = fmaxf(a, 0.f);
    }

    float g2[4] = {0.f, 0.f, 0.f, 0.f};
    #pragma unroll
    for (int c = 0; c < 16; ++c) {
        float zv = z[c];
        #pragma unroll
        for (int e = 0; e < 4; ++e) g2[e] += zv * g2s[c * 4 + e];
    }
    int idx2 = 0; float best2 = g2[0];
    #pragma unroll
    for (int e = 1; e < 4; ++e) if (g2[e] > best2) { best2 = g2[e]; idx2 = e; }
    float z2[2];
    #pragma unroll
    for (int o = 0; o < 2; ++o) {
        float a = e2bs[idx2 * 2 + o];
        #pragma unroll
        for (int c = 0; c < 16; ++c) a += z[c] * e2ws[(idx2 * 16 + c) * 2 + o];
        z2[o] = a;
    }

    float mx = fmaxf(z2[0], z2[1]);
    float l = logf(expf(z2[0] - mx) + expf(z2[1] - mx));
    out1[(size_t)m * 2 + 0] = z2[0] - mx - l;
    out1[(size_t)m * 2 + 1] = z2[1] - mx - l;
}

extern "C" void kernel_launch(void* const* d_in, const int* in_sizes, int n_in,
                              void* d_out, int out_size, void* d_ws, size_t ws_size,
                              hipStream_t stream) {
    const float* x       = (const float*)d_in[0];
    const float* w1      = (const float*)d_in[1];
    const float* b1      = (const float*)d_in[2];
    const float* w2      = (const float*)d_in[3];
    const float* b2      = (const float*)d_in[4];
    const float* gate1_w = (const float*)d_in[5];
    const float* e1_w    = (const float*)d_in[6];
    const float* e1_b    = (const float*)d_in[7];
    const float* gate2_w = (const float*)d_in[8];
    const float* e2_w    = (const float*)d_in[9];
    const float* e2_b    = (const float*)d_in[10];
    const int*   ei      = (const int*)d_in[11];
    const int*   nodes   = (const int*)d_in[12];

    const int n    = in_sizes[0] / 256;      // 100000
    const int nE   = in_sizes[11] / 2;       // 3200000
    const int nsel = in_sizes[12];           // 4096
    const int M    = nsel * 50;              // 204800
    const int nb   = (n + NPB - 1) / NPB;    // 1563

    size_t off = 0;
    auto alloc = [&](size_t bytes) -> void* {
        void* p = (char*)d_ws + off;
        off += (bytes + 255) & ~(size_t)255;
        return p;
    };
    float* dis    = (float*)alloc((size_t)n * 4);
    int*   needed = (int*)alloc((size_t)n * 4);
    int*   bhist  = (int*)alloc((size_t)nb * 4);
    int*   boffs  = (int*)alloc((size_t)(nb + 1) * 4);
    int*   gcur   = (int*)alloc((size_t)nb * 4);
    int*   keys   = (int*)alloc((size_t)nE * 4);
    float* hw1    = (float*)alloc((size_t)n * 32 * 4);
    float* hw2    = (float*)alloc((size_t)n * 16 * 4);
    float* h2     = hw1;   // hw1 dead after aggD; reuse as h2
    if (off > ws_size) return;

    float* out1 = (float*)d_out;              // [M,2]
    float* out2 = out1 + (size_t)M * 2;       // [M,32]

    zero_kernel<<<(n + 255) / 256, 256, 0, stream>>>(needed, n);
    zero_kernel<<<(nb + 255) / 256, 256, 0, stream>>>(bhist, nb);
    needed_kernel<<<(nsel + 255) / 256, 256, 0, stream>>>(nodes, needed, nsel);
    histA_kernel<<<(nE + 4095) / 4096, 256, 0, stream>>>(ei, bhist, nE, nb);
    scanB_kernel<<<1, 256, 0, stream>>>(bhist, boffs, gcur, nb);
    scatterC_kernel<<<(nE + BATCH - 1) / BATCH, 256, 0, stream>>>(ei, gcur, keys, nE, nb);
    disC2_kernel<<<nb, 256, 0, stream>>>(keys, boffs, dis, n);
    hw1_kernel<<<(n + 7) / 8, 256, 0, stream>>>(x, w1, hw1, n);
    aggD_kernel<<<nb, 256, 0, stream>>>(hw1, dis, keys, boffs, b1, w2, hw2, n);
    aggE_kernel<<<nb, 256, 0, stream>>>(hw2, dis, keys, boffs, needed, b2, h2, n);
    pair_moe_kernel<<<(M + 255) / 256, 256, 0, stream>>>(h2, nodes, gate1_w, e1_w, e1_b,
                                                         gate2_w, e2_w, e2_b, out1, out2, M);
}